// Round 4
// baseline (192.513 us; speedup 1.0000x reference)
//
#include <hip/hip_runtime.h>
#include <math.h>

#define BB 64
#define LL 512
#define DD 512
#define CC 50
#define NC 100
#define NCP 112

// ws byte layout:
//   0: loss f32   4: cnt f32   8: done counter (int)
//   64:      scomb f32 [64][112]                (28672 B)
//   28736:   span partials bf16 [4 seg][64 b][512 d]  (262144 B)
//   290880:  Wtop bf16 [112][512]  (rows 100..111 never written; excluded in epilogue)
//   405568:  Wbot bf16 [112][512]
#define WSB_LOSS  0
#define WSB_CNT   4
#define WSB_DONE  8
#define WSB_SCOMB 64
#define WSB_PART  28736
#define WSB_WTOP  290880
#define WSB_WBOT  405568

typedef __attribute__((ext_vector_type(8))) short bf16x8;
typedef __attribute__((ext_vector_type(4))) float f32x4;

static __device__ __forceinline__ unsigned short f2bf(float x) {
    unsigned int u = __float_as_uint(x);
    u += 0x7FFFu + ((u >> 16) & 1u);          // RNE
    return (unsigned short)(u >> 16);
}
static __device__ __forceinline__ float bf2f(unsigned short h) {
    return __uint_as_float(((unsigned int)h) << 16);
}

// ---------------------------------------------------------------------------
// k_prep: blocks [0,256): span partial sums. block = (b<<2)|seg; rows
//   [seg*128, seg*128+128) ∩ [start,end] summed into bf16 partial[seg][b][512].
//   Thread layout: f4-chunk c4 = t&127, row parity p = t>>7; combine via LDS.
// blocks [256,272): W transpose/convert: chunk of 128 k-rows x 50 c of
//   W_start (blocks 256..263) / W_end (264..271) -> Wtop/Wbot[n][k] bf16.
// block 256 also zeroes loss/cnt/done.
// ---------------------------------------------------------------------------
__global__ __launch_bounds__(256) void k_prep(
    const float* __restrict__ tv, const int* __restrict__ sbj_bound,
    const float* __restrict__ Wst, const float* __restrict__ Wen,
    char* __restrict__ wsb)
{
    __shared__ float sh[128 * 53];             // transpose tile; span uses first 1024
    const int t = threadIdx.x;
    const int blk = blockIdx.x;

    if (blk < 256) {
        const int b = blk >> 2, seg = blk & 3;
        const int start = sbj_bound[2 * b], end = sbj_bound[2 * b + 1];
        int r0 = seg * 128;       if (r0 < start) r0 = start;
        int r1 = seg * 128 + 127; if (r1 > end)   r1 = end;
        const int c4 = t & 127, par = t >> 7;
        const float* bp = tv + (size_t)b * LL * DD + c4 * 4;
        float4 a0 = {0, 0, 0, 0}, a1 = {0, 0, 0, 0};
        int r = r0 + par;
        for (; r + 2 <= r1; r += 4) {
            float4 v0 = *(const float4*)(bp + (size_t)r * DD);
            float4 v1 = *(const float4*)(bp + (size_t)(r + 2) * DD);
            a0.x += v0.x; a0.y += v0.y; a0.z += v0.z; a0.w += v0.w;
            a1.x += v1.x; a1.y += v1.y; a1.z += v1.z; a1.w += v1.w;
        }
        for (; r <= r1; r += 2) {
            float4 v0 = *(const float4*)(bp + (size_t)r * DD);
            a0.x += v0.x; a0.y += v0.y; a0.z += v0.z; a0.w += v0.w;
        }
        float4* buf = (float4*)sh;
        float4 acc = {a0.x + a1.x, a0.y + a1.y, a0.z + a1.z, a0.w + a1.w};
        buf[t] = acc;
        __syncthreads();
        if (t < 128) {
            float4 x = buf[t], y = buf[t + 128];
            unsigned short* part = (unsigned short*)(wsb + WSB_PART);
            ushort4 o;
            o.x = f2bf(x.x + y.x); o.y = f2bf(x.y + y.y);
            o.z = f2bf(x.z + y.z); o.w = f2bf(x.w + y.w);
            *(ushort4*)(part + ((size_t)(seg * BB + b)) * DD + t * 4) = o;
        }
    } else {
        const int bi = blk - 256;              // 0..15
        const int mat = bi >> 3;               // 0: W_start, 1: W_end
        const int cj = bi & 7;                 // 128-row k-chunk of [0,1024)
        const float* W = mat ? Wen : Wst;
        const int kbase = cj * 128;
        const float* src = W + (size_t)kbase * CC;
#pragma unroll
        for (int i = 0; i < 25; i++) {
            int idx = t + i * 256;             // [0,6400)
            int kr = idx / 50, c = idx - kr * 50;
            sh[kr * 53 + c] = src[idx];
        }
        __syncthreads();
        unsigned short* outp =
            (unsigned short*)(wsb + ((cj < 4) ? WSB_WTOP : WSB_WBOT));
        const int kout = kbase & 511;
#pragma unroll
        for (int i = 0; i < 25; i++) {
            int idx = t + i * 256;             // 50 n x 128 k
            int n = idx >> 7, kl = idx & 127;
            outp[((size_t)(mat * CC + n)) * DD + kout + kl] = f2bf(sh[kl * 53 + n]);
        }
        if (bi == 0 && t == 0) {
            *(float*)(wsb + WSB_LOSS) = 0.0f;
            *(float*)(wsb + WSB_CNT)  = 0.0f;
            *(int*)(wsb + WSB_DONE)   = 0;
        }
    }
}

// ---------------------------------------------------------------------------
// k_scomb: ONE block. Phase 1: combine 4 bf16 seg-partials -> sbj bf16 [64][520]
// in LDS (divided by span count). Phase 2: MFMA GEMM sbj(64x512) @ Wbot^T
// -> scomb[b][cc] (+bias), f32 in ws.
// ---------------------------------------------------------------------------
__global__ __launch_bounds__(256) void k_scomb(
    const int* __restrict__ sbj_bound,
    const float* __restrict__ bst, const float* __restrict__ ben,
    char* __restrict__ wsb)
{
    __shared__ __align__(16) unsigned short sbjb[64 * 520];
    const int t = threadIdx.x;
    const unsigned short* part = (const unsigned short*)(wsb + WSB_PART);

#pragma unroll 4
    for (int i = 0; i < 32; i++) {
        int idx = t + i * 256;                 // [0, 8192)
        int b = idx >> 7;                      // 128 f4-groups per b
        int d4 = idx & 127;
        float inv = 1.0f / (float)(sbj_bound[2 * b + 1] - sbj_bound[2 * b] + 1);
        float sx = 0.f, sy = 0.f, sz = 0.f, sw = 0.f;
#pragma unroll
        for (int seg = 0; seg < 4; seg++) {
            ushort4 v = *(const ushort4*)(part + ((size_t)(seg * BB + b)) * DD + d4 * 4);
            sx += bf2f(v.x); sy += bf2f(v.y); sz += bf2f(v.z); sw += bf2f(v.w);
        }
        ushort4 o;
        o.x = f2bf(sx * inv); o.y = f2bf(sy * inv);
        o.z = f2bf(sz * inv); o.w = f2bf(sw * inv);
        *(ushort4*)(sbjb + b * 520 + d4 * 4) = o;
    }
    __syncthreads();

    const int wv = t >> 6, ln = t & 63, tc = ln & 15, quad = ln >> 4;
    const unsigned short* wbot = (const unsigned short*)(wsb + WSB_WBOT);
    f32x4 acc[7];
#pragma unroll
    for (int u = 0; u < 7; u++) acc[u] = (f32x4)(0.0f);
    const unsigned short* Af = sbjb + (wv * 16 + tc) * 520 + quad * 8;
    const unsigned short* Bf = wbot + (size_t)tc * DD + quad * 8;
#pragma unroll 4
    for (int kk = 0; kk < DD; kk += 32) {
        bf16x8 af = *(const bf16x8*)(Af + kk);
#pragma unroll
        for (int u = 0; u < 7; u++) {
            bf16x8 bf = *(const bf16x8*)(Bf + (size_t)u * 16 * DD + kk);
            acc[u] = __builtin_amdgcn_mfma_f32_16x16x32_bf16(af, bf, acc[u], 0, 0, 0);
        }
    }
    float* scomb = (float*)(wsb + WSB_SCOMB);
#pragma unroll
    for (int u = 0; u < 7; u++) {
        int cc = u * 16 + tc;
        if (cc < NC) {
            float bias = (cc < CC) ? bst[cc] : ben[cc - CC];
#pragma unroll
            for (int i = 0; i < 4; i++) {
                int b = wv * 16 + quad * 4 + i;
                scomb[b * NCP + cc] = acc[u][i] + bias;
            }
        }
    }
}

// ---------------------------------------------------------------------------
// k_main: barrier-free bf16 MFMA GEMM + fused CE. Each wave: 16 rows x 112
// cols, K=512. A f32 fragments loaded direct from global (converted in regs),
// B bf16 fragments direct from L2-resident Wtop. Final block computes out.
// ---------------------------------------------------------------------------
__global__ __launch_bounds__(256) void k_main(
    const float* __restrict__ tv,
    const int* __restrict__ mask,
    const int* __restrict__ obj_s, const int* __restrict__ obj_e,
    char* __restrict__ wsb, float* __restrict__ out)
{
    __shared__ float red[8];
    const int t = threadIdx.x, wv = t >> 6, ln = t & 63;
    const int tc = ln & 15, quad = ln >> 4;
    const int m0 = (blockIdx.x * 4 + wv) * 16;
    const int b = m0 >> 9;
    const unsigned short* wtop = (const unsigned short*)(wsb + WSB_WTOP);
    const float* scomb = (const float*)(wsb + WSB_SCOMB);

    // hoist epilogue data (hides latency under the GEMM)
    float sc[7];
#pragma unroll
    for (int u = 0; u < 7; u++) sc[u] = scomb[b * NCP + u * 16 + tc];
    int lab1[4], lab2[4], mk[4];
#pragma unroll
    for (int i = 0; i < 4; i++) {
        int l = (m0 + quad * 4 + i) & (LL - 1);
        lab1[i] = obj_s[b * LL + l];
        lab2[i] = obj_e[b * LL + l] + CC;
        mk[i]   = mask[b * LL + l];
    }

    const float* Abase = tv + (size_t)(m0 + tc) * DD + quad * 8;
    const unsigned short* Bbase = wtop + (size_t)tc * DD + quad * 8;
    f32x4 acc[7];
#pragma unroll
    for (int u = 0; u < 7; u++) acc[u] = (f32x4)(0.0f);

#pragma unroll 4
    for (int kk = 0; kk < DD; kk += 32) {
        float4 v0 = *(const float4*)(Abase + kk);
        float4 v1 = *(const float4*)(Abase + kk + 4);
        bf16x8 af;
        af[0] = (short)f2bf(v0.x); af[1] = (short)f2bf(v0.y);
        af[2] = (short)f2bf(v0.z); af[3] = (short)f2bf(v0.w);
        af[4] = (short)f2bf(v1.x); af[5] = (short)f2bf(v1.y);
        af[6] = (short)f2bf(v1.z); af[7] = (short)f2bf(v1.w);
#pragma unroll
        for (int u = 0; u < 7; u++) {
            bf16x8 bf = *(const bf16x8*)(Bbase + (size_t)u * 16 * DD + kk);
            acc[u] = __builtin_amdgcn_mfma_f32_16x16x32_bf16(af, bf, acc[u], 0, 0, 0);
        }
    }

    // ---- fused CE epilogue (C/D layout: col=lane&15, row=quad*4+reg) ----
    float loss_local = 0.0f, cnt_local = 0.0f;
#pragma unroll
    for (int i = 0; i < 4; i++) {
        float lg[7];
#pragma unroll
        for (int u = 0; u < 7; u++) lg[u] = acc[u][i] + sc[u];
        float m1 = fmaxf(fmaxf(lg[0], lg[1]), lg[2]);
        if (tc < 2) m1 = fmaxf(m1, lg[3]);
        float m2 = fmaxf(lg[4], lg[5]);
        if (tc >= 2) m2 = fmaxf(m2, lg[3]);
        if (tc < 4)  m2 = fmaxf(m2, lg[6]);
#pragma unroll
        for (int off = 1; off < 16; off <<= 1) {
            m1 = fmaxf(m1, __shfl_xor(m1, off, 16));
            m2 = fmaxf(m2, __shfl_xor(m2, off, 16));
        }
        float e1 = expf(lg[0] - m1) + expf(lg[1] - m1) + expf(lg[2] - m1)
                 + ((tc < 2) ? expf(lg[3] - m1) : 0.0f);
        float e2 = expf(lg[4] - m2) + expf(lg[5] - m2)
                 + ((tc >= 2) ? expf(lg[3] - m2) : 0.0f)
                 + ((tc < 4)  ? expf(lg[6] - m2) : 0.0f);
        float t1 = 0.0f, t2 = 0.0f;
#pragma unroll
        for (int u = 0; u < 7; u++) {
            const int cc = u * 16 + tc;
            if (cc == lab1[i]) t1 = lg[u];
            if (cc == lab2[i]) t2 = lg[u];
        }
#pragma unroll
        for (int off = 1; off < 16; off <<= 1) {
            e1 += __shfl_xor(e1, off, 16);
            e2 += __shfl_xor(e2, off, 16);
            t1 += __shfl_xor(t1, off, 16);
            t2 += __shfl_xor(t2, off, 16);
        }
        if (tc == 0) {
            const float nll = (m1 + logf(e1) - t1) + (m2 + logf(e2) - t2);
            loss_local += mk[i] ? nll : 0.0f;
            cnt_local  += mk[i] ? 1.0f : 0.0f;
        }
    }
#pragma unroll
    for (int off = 1; off < 64; off <<= 1) {
        loss_local += __shfl_xor(loss_local, off);
        cnt_local  += __shfl_xor(cnt_local, off);
    }
    if (ln == 0) { red[wv * 2] = loss_local; red[wv * 2 + 1] = cnt_local; }
    __syncthreads();
    if (t == 0) {
        float* wsf = (float*)wsb;
        atomicAdd(&wsf[0], red[0] + red[2] + red[4] + red[6]);
        atomicAdd(&wsf[1], red[1] + red[3] + red[5] + red[7]);
        __threadfence();
        int old = atomicAdd((int*)(wsb + WSB_DONE), 1);
        if (old == (int)gridDim.x - 1) {
            float L = atomicAdd(&wsf[0], 0.0f);   // atomic read (coherent)
            float C = atomicAdd(&wsf[1], 0.0f);
            out[0] = L / C;
        }
    }
}

extern "C" void kernel_launch(void* const* d_in, const int* in_sizes, int n_in,
                              void* d_out, int out_size, void* d_ws, size_t ws_size,
                              hipStream_t stream) {
    const float* tv   = (const float*)d_in[0];
    const int*   mask = (const int*)d_in[1];
    const int*   sbj  = (const int*)d_in[2];
    const int*   objs = (const int*)d_in[3];
    const int*   obje = (const int*)d_in[4];
    const float* Wst  = (const float*)d_in[5];
    const float* bst  = (const float*)d_in[6];
    const float* Wen  = (const float*)d_in[7];
    const float* ben  = (const float*)d_in[8];
    float* out = (float*)d_out;
    char*  wsb = (char*)d_ws;

    k_prep<<<272, 256, 0, stream>>>(tv, sbj, Wst, Wen, wsb);
    k_scomb<<<1, 256, 0, stream>>>(sbj, bst, ben, wsb);
    k_main<<<512, 256, 0, stream>>>(tv, mask, objs, obje, wsb, out);
}

// Round 5
// 141.360 us; speedup vs baseline: 1.3619x; 1.3619x over previous
//
#include <hip/hip_runtime.h>
#include <math.h>

#define BB 64
#define LL 512
#define DD 512
#define CC 50
#define NC 100
#define NCP 112
#define WST 520     // LDS row stride (bf16 units): bank step 4 -> 2-way max

// ws byte layout:
//   0: loss f32   4: cnt f32   8: done counter (int)
//   64:      scomb f32 [64][112]                   (28672 B)
//   28736:   span partials bf16 [8 seg][64 b][512] (524288 B)
//   553024:  Wtop bf16 [112][512] (rows 100..111 = poison, excluded in epilogue)
//   667712:  Wbot bf16 [112][512]
#define WSB_LOSS  0
#define WSB_CNT   4
#define WSB_DONE  8
#define WSB_SCOMB 64
#define WSB_PART  28736
#define WSB_WTOP  553024
#define WSB_WBOT  667712

typedef __attribute__((ext_vector_type(8))) short bf16x8;
typedef __attribute__((ext_vector_type(4))) float f32x4;

static __device__ __forceinline__ unsigned short f2bf(float x) {
    unsigned int u = __float_as_uint(x);
    u += 0x7FFFu + ((u >> 16) & 1u);          // RNE
    return (unsigned short)(u >> 16);
}
static __device__ __forceinline__ float bf2f(unsigned short h) {
    return __uint_as_float(((unsigned int)h) << 16);
}

// ---------------------------------------------------------------------------
// k_prep: blocks [0,512): span partials. block=(b<<3)|seg; rows
//   [seg*64, seg*64+64) ∩ [start,end] summed -> bf16 partial[seg][b][512].
//   Empty segments write ZEROS (no early return).
// blocks [512,528): W transpose/convert -> Wtop/Wbot bf16 [100][512].
// block 512 zeroes loss/cnt/done.
// ---------------------------------------------------------------------------
__global__ __launch_bounds__(256) void k_prep(
    const float* __restrict__ tv, const int* __restrict__ sbj_bound,
    const float* __restrict__ Wst, const float* __restrict__ Wen,
    char* __restrict__ wsb)
{
    __shared__ float sh[128 * 53];
    const int t = threadIdx.x;
    const int blk = blockIdx.x;

    if (blk < 512) {
        const int b = blk >> 3, seg = blk & 7;
        const int start = sbj_bound[2 * b], end = sbj_bound[2 * b + 1];
        int r0 = seg * 64;      if (r0 < start) r0 = start;
        int r1 = seg * 64 + 63; if (r1 > end)   r1 = end;
        const int c4 = t & 127, par = t >> 7;
        const float* bp = tv + (size_t)b * LL * DD + c4 * 4;
        float4 a0 = {0, 0, 0, 0}, a1 = {0, 0, 0, 0};
        int r = r0 + par;
        for (; r + 2 <= r1; r += 4) {
            float4 v0 = *(const float4*)(bp + (size_t)r * DD);
            float4 v1 = *(const float4*)(bp + (size_t)(r + 2) * DD);
            a0.x += v0.x; a0.y += v0.y; a0.z += v0.z; a0.w += v0.w;
            a1.x += v1.x; a1.y += v1.y; a1.z += v1.z; a1.w += v1.w;
        }
        for (; r <= r1; r += 2) {
            float4 v0 = *(const float4*)(bp + (size_t)r * DD);
            a0.x += v0.x; a0.y += v0.y; a0.z += v0.z; a0.w += v0.w;
        }
        float4* buf = (float4*)sh;
        float4 acc = {a0.x + a1.x, a0.y + a1.y, a0.z + a1.z, a0.w + a1.w};
        buf[t] = acc;
        __syncthreads();
        if (t < 128) {
            float4 x = buf[t], y = buf[t + 128];
            unsigned short* part = (unsigned short*)(wsb + WSB_PART);
            ushort4 o;
            o.x = f2bf(x.x + y.x); o.y = f2bf(x.y + y.y);
            o.z = f2bf(x.z + y.z); o.w = f2bf(x.w + y.w);
            *(ushort4*)(part + ((size_t)(seg * BB + b)) * DD + t * 4) = o;
        }
    } else {
        const int bi = blk - 512;              // 0..15
        const int mat = bi >> 3;               // 0: W_start, 1: W_end
        const int cj = bi & 7;                 // 128-row k-chunk of [0,1024)
        const float* W = mat ? Wen : Wst;
        const int kbase = cj * 128;
        const float* src = W + (size_t)kbase * CC;
#pragma unroll
        for (int i = 0; i < 25; i++) {
            int idx = t + i * 256;             // [0,6400)
            int kr = idx / 50, c = idx - kr * 50;
            sh[kr * 53 + c] = src[idx];
        }
        __syncthreads();
        unsigned short* outp =
            (unsigned short*)(wsb + ((cj < 4) ? WSB_WTOP : WSB_WBOT));
        const int kout = kbase & 511;
#pragma unroll
        for (int i = 0; i < 25; i++) {
            int idx = t + i * 256;             // 50 n x 128 k
            int n = idx >> 7, kl = idx & 127;
            outp[((size_t)(mat * CC + n)) * DD + kout + kl] = f2bf(sh[kl * 53 + n]);
        }
        if (bi == 0 && t == 0) {
            *(float*)(wsb + WSB_LOSS) = 0.0f;
            *(float*)(wsb + WSB_CNT)  = 0.0f;
            *(int*)(wsb + WSB_DONE)   = 0;
        }
    }
}

// ---------------------------------------------------------------------------
// k_scomb: 4 blocks x 16 batches. Phase 1: combine 8 bf16 seg-partials ->
// sbj bf16 [16][520] LDS (div by span count). Phase 2: per-wave column strips
// (u = {0,1},{2,3},{4,5},{6}) of sbj(16x512) @ Wbot^T -> scomb f32 (+bias).
// ---------------------------------------------------------------------------
__global__ __launch_bounds__(256) void k_scomb(
    const int* __restrict__ sbj_bound,
    const float* __restrict__ bst, const float* __restrict__ ben,
    char* __restrict__ wsb)
{
    __shared__ __align__(16) unsigned short sbjb[16 * WST];
    const int t = threadIdx.x;
    const int g = blockIdx.x;
    const unsigned short* part = (const unsigned short*)(wsb + WSB_PART);

#pragma unroll
    for (int i = 0; i < 8; i++) {
        int idx = t + i * 256;                 // [0, 2048)
        int bo = idx >> 7, d4 = idx & 127;
        int b = g * 16 + bo;
        float inv = 1.0f / (float)(sbj_bound[2 * b + 1] - sbj_bound[2 * b] + 1);
        float sx = 0.f, sy = 0.f, sz = 0.f, sw = 0.f;
#pragma unroll
        for (int seg = 0; seg < 8; seg++) {
            ushort4 v = *(const ushort4*)(part + ((size_t)(seg * BB + b)) * DD + d4 * 4);
            sx += bf2f(v.x); sy += bf2f(v.y); sz += bf2f(v.z); sw += bf2f(v.w);
        }
        ushort4 o;
        o.x = f2bf(sx * inv); o.y = f2bf(sy * inv);
        o.z = f2bf(sz * inv); o.w = f2bf(sw * inv);
        *(ushort4*)(sbjb + bo * WST + d4 * 4) = o;
    }
    __syncthreads();

    const int wv = t >> 6, ln = t & 63, tc = ln & 15, quad = ln >> 4;
    const unsigned short* wbot = (const unsigned short*)(wsb + WSB_WBOT);
    float* scomb = (float*)(wsb + WSB_SCOMB);
    const unsigned short* Af = sbjb + tc * WST + quad * 8;
    const int nu = (wv < 3) ? 2 : 1;
    for (int j = 0; j < nu; j++) {
        const int u = wv * 2 + j;
        f32x4 acc = (f32x4)(0.0f);
        const unsigned short* Bf = wbot + (size_t)(u * 16 + tc) * DD + quad * 8;
#pragma unroll
        for (int kk = 0; kk < DD; kk += 32) {
            bf16x8 af = *(const bf16x8*)(Af + kk);
            bf16x8 bf = *(const bf16x8*)(Bf + kk);
            acc = __builtin_amdgcn_mfma_f32_16x16x32_bf16(af, bf, acc, 0, 0, 0);
        }
        const int cc = u * 16 + tc;
        const float bias = (cc < CC) ? bst[cc] : ((cc < NC) ? ben[cc - CC] : 0.0f);
#pragma unroll
        for (int i = 0; i < 4; i++) {
            int b = g * 16 + quad * 4 + i;
            scomb[b * NCP + cc] = acc[i] + bias;
        }
    }
}

// ---------------------------------------------------------------------------
// k_main: 256 blocks x 512 thr (1 block/CU, 8 waves). Stage full B (112x520
// bf16) in LDS once; preload ALL A (16 rows x 512 k per wave) in two register
// batches; one barrier; pure LDS+MFMA burst; fused CE epilogue.
// ---------------------------------------------------------------------------
__global__ __launch_bounds__(512, 2) void k_main(
    const float* __restrict__ tv,
    const int* __restrict__ mask,
    const int* __restrict__ obj_s, const int* __restrict__ obj_e,
    char* __restrict__ wsb, float* __restrict__ out)
{
    __shared__ __align__(16) unsigned short Wt[NCP * WST];   // 116480 B
    __shared__ float red[16];
    const int t = threadIdx.x, wv = t >> 6, ln = t & 63;
    const int tc = ln & 15, quad = ln >> 4;
    const int m0w = blockIdx.x * 128 + wv * 16;
    const int b = blockIdx.x >> 2;
    const unsigned short* wtop = (const unsigned short*)(wsb + WSB_WTOP);

    const float* Abase = tv + (size_t)(m0w + tc) * DD + quad * 8;

    // A preload, K-half 0 (k 0..255): 16 float4 in flight
    float4 alo[16];
#pragma unroll
    for (int j = 0; j < 8; j++) {
        alo[2 * j]     = *(const float4*)(Abase + j * 32);
        alo[2 * j + 1] = *(const float4*)(Abase + j * 32 + 4);
    }
    // stage B: 112 rows x 64 chunks-of-8 = 7168; 14 per thread, coalesced
#pragma unroll
    for (int i = 0; i < 14; i++) {
        int idx = t + i * 512;
        int n = idx >> 6, ch = idx & 63;
        *(bf16x8*)(Wt + n * WST + ch * 8) =
            *(const bf16x8*)(wtop + (size_t)n * DD + ch * 8);
    }
    // A preload, K-half 1 (k 256..511)
    float4 ahi[16];
#pragma unroll
    for (int j = 0; j < 8; j++) {
        ahi[2 * j]     = *(const float4*)(Abase + 256 + j * 32);
        ahi[2 * j + 1] = *(const float4*)(Abase + 256 + j * 32 + 4);
    }
    __syncthreads();

    f32x4 acc[7];
#pragma unroll
    for (int u = 0; u < 7; u++) acc[u] = (f32x4)(0.0f);
    const unsigned short* Wf = Wt + tc * WST + quad * 8;

#pragma unroll
    for (int j = 0; j < 8; j++) {
        float4 v0 = alo[2 * j], v1 = alo[2 * j + 1];
        bf16x8 af;
        af[0] = (short)f2bf(v0.x); af[1] = (short)f2bf(v0.y);
        af[2] = (short)f2bf(v0.z); af[3] = (short)f2bf(v0.w);
        af[4] = (short)f2bf(v1.x); af[5] = (short)f2bf(v1.y);
        af[6] = (short)f2bf(v1.z); af[7] = (short)f2bf(v1.w);
#pragma unroll
        for (int u = 0; u < 7; u++) {
            bf16x8 bf = *(const bf16x8*)(Wf + u * 16 * WST + j * 32);
            acc[u] = __builtin_amdgcn_mfma_f32_16x16x32_bf16(af, bf, acc[u], 0, 0, 0);
        }
    }
#pragma unroll
    for (int j = 0; j < 8; j++) {
        float4 v0 = ahi[2 * j], v1 = ahi[2 * j + 1];
        bf16x8 af;
        af[0] = (short)f2bf(v0.x); af[1] = (short)f2bf(v0.y);
        af[2] = (short)f2bf(v0.z); af[3] = (short)f2bf(v0.w);
        af[4] = (short)f2bf(v1.x); af[5] = (short)f2bf(v1.y);
        af[6] = (short)f2bf(v1.z); af[7] = (short)f2bf(v1.w);
#pragma unroll
        for (int u = 0; u < 7; u++) {
            bf16x8 bf = *(const bf16x8*)(Wf + u * 16 * WST + 256 + j * 32);
            acc[u] = __builtin_amdgcn_mfma_f32_16x16x32_bf16(af, bf, acc[u], 0, 0, 0);
        }
    }

    // ---- fused CE epilogue (C/D: col=lane&15, row=quad*4+reg) ----
    const float* scomb = (const float*)(wsb + WSB_SCOMB);
    float sc[7];
#pragma unroll
    for (int u = 0; u < 7; u++) sc[u] = scomb[b * NCP + u * 16 + tc];

    float loss_local = 0.0f, cnt_local = 0.0f;
#pragma unroll
    for (int i = 0; i < 4; i++) {
        const int l = (m0w + quad * 4 + i) & (LL - 1);
        const int lab1 = obj_s[b * LL + l];
        const int lab2 = obj_e[b * LL + l] + CC;
        const int mk   = mask[b * LL + l];
        float lg[7];
#pragma unroll
        for (int u = 0; u < 7; u++) lg[u] = acc[u][i] + sc[u];
        float m1 = fmaxf(fmaxf(lg[0], lg[1]), lg[2]);
        if (tc < 2) m1 = fmaxf(m1, lg[3]);
        float m2 = fmaxf(lg[4], lg[5]);
        if (tc >= 2) m2 = fmaxf(m2, lg[3]);
        if (tc < 4)  m2 = fmaxf(m2, lg[6]);
#pragma unroll
        for (int off = 1; off < 16; off <<= 1) {
            m1 = fmaxf(m1, __shfl_xor(m1, off, 16));
            m2 = fmaxf(m2, __shfl_xor(m2, off, 16));
        }
        float e1 = expf(lg[0] - m1) + expf(lg[1] - m1) + expf(lg[2] - m1)
                 + ((tc < 2) ? expf(lg[3] - m1) : 0.0f);
        float e2 = expf(lg[4] - m2) + expf(lg[5] - m2)
                 + ((tc >= 2) ? expf(lg[3] - m2) : 0.0f)
                 + ((tc < 4)  ? expf(lg[6] - m2) : 0.0f);
        float t1 = 0.0f, t2 = 0.0f;
#pragma unroll
        for (int u = 0; u < 7; u++) {
            const int cc = u * 16 + tc;
            if (cc == lab1) t1 = lg[u];
            if (cc == lab2) t2 = lg[u];
        }
#pragma unroll
        for (int off = 1; off < 16; off <<= 1) {
            e1 += __shfl_xor(e1, off, 16);
            e2 += __shfl_xor(e2, off, 16);
            t1 += __shfl_xor(t1, off, 16);
            t2 += __shfl_xor(t2, off, 16);
        }
        if (tc == 0) {
            const float nll = (m1 + logf(e1) - t1) + (m2 + logf(e2) - t2);
            loss_local += mk ? nll : 0.0f;
            cnt_local  += mk ? 1.0f : 0.0f;
        }
    }
#pragma unroll
    for (int off = 1; off < 64; off <<= 1) {
        loss_local += __shfl_xor(loss_local, off);
        cnt_local  += __shfl_xor(cnt_local, off);
    }
    if (ln == 0) { red[wv * 2] = loss_local; red[wv * 2 + 1] = cnt_local; }
    __syncthreads();
    if (t == 0) {
        float Ls = 0.f, Cs = 0.f;
#pragma unroll
        for (int w = 0; w < 8; w++) { Ls += red[w * 2]; Cs += red[w * 2 + 1]; }
        float* wsf = (float*)wsb;
        atomicAdd(&wsf[0], Ls);
        atomicAdd(&wsf[1], Cs);
        __threadfence();
        int old = atomicAdd((int*)(wsb + WSB_DONE), 1);
        if (old == (int)gridDim.x - 1) {
            float L = atomicAdd(&wsf[0], 0.0f);   // coherent read
            float C = atomicAdd(&wsf[1], 0.0f);
            out[0] = L / C;
        }
    }
}

extern "C" void kernel_launch(void* const* d_in, const int* in_sizes, int n_in,
                              void* d_out, int out_size, void* d_ws, size_t ws_size,
                              hipStream_t stream) {
    const float* tv   = (const float*)d_in[0];
    const int*   mask = (const int*)d_in[1];
    const int*   sbj  = (const int*)d_in[2];
    const int*   objs = (const int*)d_in[3];
    const int*   obje = (const int*)d_in[4];
    const float* Wst  = (const float*)d_in[5];
    const float* bst  = (const float*)d_in[6];
    const float* Wen  = (const float*)d_in[7];
    const float* ben  = (const float*)d_in[8];
    float* out = (float*)d_out;
    char*  wsb = (char*)d_ws;

    k_prep<<<528, 256, 0, stream>>>(tv, sbj, Wst, Wen, wsb);
    k_scomb<<<4, 256, 0, stream>>>(sbj, bst, ben, wsb);
    k_main<<<256, 512, 0, stream>>>(tv, mask, objs, obje, wsb, out);
}